// Round 5
// baseline (85.377 us; speedup 1.0000x reference)
//
#include <hip/hip_runtime.h>

#define PCX 512.0f
#define PCY 512.0f
#define VCHUNK 32

typedef float f32x2 __attribute__((ext_vector_type(2)));
typedef float f32x4 __attribute__((ext_vector_type(4)));

// ---------------------------------------------------------------------------
// Setup: compose R = Rx(a)@Ry(b)@Rz(c), fold focal + sign + trans:
//   m[0..2] = -f*row0, c0 = -f*tx   ->  u = (m.P + c0)*(1/Z) + CX
//   m[3..5] =  f*row1, c1 =  f*ty   ->  v = (m.P + c1)*(1/Z) + CY
//   m[6..8] =    row2, c2 =     tz  ->  Z =  m.P + c2
// ---------------------------------------------------------------------------
__global__ void setup_R_kernel(const float* __restrict__ eulers,
                               const float* __restrict__ trans,
                               const float* __restrict__ focal_p,
                               float* __restrict__ Rt, int V) {
    int v = blockIdx.x * blockDim.x + threadIdx.x;
    if (v >= V) return;
    const float f = *focal_p;
    float a = eulers[3 * v + 0], b = eulers[3 * v + 1], c = eulers[3 * v + 2];
    float sa, ca, sb, cb, sc, cc;
    sincosf(a, &sa, &ca);
    sincosf(b, &sb, &cb);
    sincosf(c, &sc, &cc);
    const float r00 = cb * cc,                 r01 = -cb * sc,                r02 = sb;
    const float r10 = ca * sc + sa * sb * cc,  r11 = ca * cc - sa * sb * sc,  r12 = -sa * cb;
    const float r20 = sa * sc - ca * sb * cc,  r21 = sa * cc + ca * sb * sc,  r22 = ca * cb;
    float* o = Rt + 12 * v;
    o[0] = -f * r00;  o[1] = -f * r01;  o[2] = -f * r02;
    o[3] =  f * r10;  o[4] =  f * r11;  o[5] =  f * r12;
    o[6] =  r20;      o[7] =  r21;      o[8] =  r22;
    o[9]  = -f * trans[3 * v + 0];
    o[10] =  f * trans[3 * v + 1];
    o[11] =  trans[3 * v + 2];
}

// ---------------------------------------------------------------------------
// Main kernel: each thread owns 2 points (registers), loops over VCHUNK views.
// Camera params read directly from global with wave-uniform addresses
// (-> s_load, K$-resident). Plain cached stores (no NT): float4 uv + float2 z,
// both unit-stride across lanes.
// ---------------------------------------------------------------------------
__global__ void __launch_bounds__(256)
proj_kernel(const f32x2* __restrict__ pts2,
            const float* __restrict__ Rt,
            float* __restrict__ out,
            int N, int Npairs, long long VN, int V) {
    const int t = blockIdx.x * blockDim.x + threadIdx.x;
    if (t >= Npairs) return;
    const int v0 = blockIdx.y * VCHUNK;
    const int vend = min(v0 + VCHUNK, V);

    const bool hasP1 = (2 * t + 1 < N);
    // load 2 points = 6 floats as 3x float2 (24B contiguous per thread)
    const f32x2 A = pts2[3 * t + 0];
    const f32x2 B = hasP1 ? pts2[3 * t + 1] : f32x2{0.f, 0.f};
    const f32x2 C = hasP1 ? pts2[3 * t + 2] : f32x2{pts2[3 * t + 1].x, 0.f};
    const float x0 = A.x, y0 = A.y;
    const float z0 = hasP1 ? B.x : C.x;
    const float x1 = B.y, y1 = C.x, z1 = C.y;

    const bool vec = ((N & 1) == 0) && hasP1;
    f32x4* __restrict__ uvp4 = reinterpret_cast<f32x4*>(out);
    f32x2* __restrict__ zp2  = reinterpret_cast<f32x2*>(out + 2 * VN);
    const int halfN = N >> 1;

    for (int v = v0; v < vend; ++v) {
        // wave-uniform address -> scalar loads, K$-resident (6 KB table)
        const float* __restrict__ p = Rt + 12 * v;
        const float m0 = p[0], m1 = p[1], m2 = p[2];
        const float m3 = p[3], m4 = p[4], m5 = p[5];
        const float m6 = p[6], m7 = p[7], m8 = p[8];
        const float c0 = p[9], c1 = p[10], c2 = p[11];

        const float X0 = fmaf(m0, x0, fmaf(m1, y0, fmaf(m2, z0, c0)));
        const float Y0 = fmaf(m3, x0, fmaf(m4, y0, fmaf(m5, z0, c1)));
        const float Z0 = fmaf(m6, x0, fmaf(m7, y0, fmaf(m8, z0, c2)));
        const float r0 = __builtin_amdgcn_rcpf(Z0);
        const float u0 = fmaf(X0, r0, PCX);
        const float w0 = fmaf(Y0, r0, PCY);

        const float X1 = fmaf(m0, x1, fmaf(m1, y1, fmaf(m2, z1, c0)));
        const float Y1 = fmaf(m3, x1, fmaf(m4, y1, fmaf(m5, z1, c1)));
        const float Z1 = fmaf(m6, x1, fmaf(m7, y1, fmaf(m8, z1, c2)));
        const float r1 = __builtin_amdgcn_rcpf(Z1);
        const float u1 = fmaf(X1, r1, PCX);
        const float w1 = fmaf(Y1, r1, PCY);

        if (vec) {
            f32x4 uvv; uvv.x = u0; uvv.y = w0; uvv.z = u1; uvv.w = w1;
            f32x2 zz;  zz.x = Z0;  zz.y = Z1;
            uvp4[(long long)v * halfN + t] = uvv;
            zp2[(long long)v * halfN + t] = zz;
        } else {
            const long long n = 2LL * t;
            const long long idx = (long long)v * N + n;
            out[2 * idx + 0] = u0;
            out[2 * idx + 1] = w0;
            out[2 * VN + idx] = Z0;
            if (hasP1) {
                out[2 * idx + 2] = u1;
                out[2 * idx + 3] = w1;
                out[2 * VN + idx + 1] = Z1;
            }
        }
    }
}

extern "C" void kernel_launch(void* const* d_in, const int* in_sizes, int n_in,
                              void* d_out, int out_size, void* d_ws, size_t ws_size,
                              hipStream_t stream) {
    const float* focal  = (const float*)d_in[0];
    const float* eulers = (const float*)d_in[1];
    const float* trans  = (const float*)d_in[2];
    const float* pts    = (const float*)d_in[3];

    const int V = in_sizes[1] / 3;
    const int N = in_sizes[3] / 3;
    const int Npairs = (N + 1) / 2;
    const long long VN = (long long)V * N;

    float* out = (float*)d_out;
    float* Rt  = (float*)d_ws;   // 12*V floats

    setup_R_kernel<<<dim3((V + 63) / 64), dim3(64), 0, stream>>>(
        eulers, trans, focal, Rt, V);

    dim3 block(256, 1, 1);
    dim3 grid((Npairs + 255) / 256, (V + VCHUNK - 1) / VCHUNK, 1);
    proj_kernel<<<grid, block, 0, stream>>>(
        reinterpret_cast<const f32x2*>(pts), Rt, out, N, Npairs, VN, V);
}

// Round 6
// 72.453 us; speedup vs baseline: 1.1784x; 1.1784x over previous
//
#include <hip/hip_runtime.h>

#define PCX 512.0f
#define PCY 512.0f

typedef float f32x2 __attribute__((ext_vector_type(2)));
typedef float f32x4 __attribute__((ext_vector_type(4)));

// ---------------------------------------------------------------------------
// Setup: compose R = Rx(a)@Ry(b)@Rz(c), fold focal + sign + trans:
//   m[0..2] = -f*row0, c0 = -f*tx   ->  u = (m.P + c0)*(1/Z) + CX
//   m[3..5] =  f*row1, c1 =  f*ty   ->  v = (m.P + c1)*(1/Z) + CY
//   m[6..8] =    row2, c2 =     tz  ->  Z =  m.P + c2
// ---------------------------------------------------------------------------
__global__ void setup_R_kernel(const float* __restrict__ eulers,
                               const float* __restrict__ trans,
                               const float* __restrict__ focal_p,
                               float* __restrict__ Rt, int V) {
    int v = blockIdx.x * blockDim.x + threadIdx.x;
    if (v >= V) return;
    const float f = *focal_p;
    float a = eulers[3 * v + 0], b = eulers[3 * v + 1], c = eulers[3 * v + 2];
    float sa, ca, sb, cb, sc, cc;
    sincosf(a, &sa, &ca);
    sincosf(b, &sb, &cb);
    sincosf(c, &sc, &cc);
    const float r00 = cb * cc,                 r01 = -cb * sc,                r02 = sb;
    const float r10 = ca * sc + sa * sb * cc,  r11 = ca * cc - sa * sb * sc,  r12 = -sa * cb;
    const float r20 = sa * sc - ca * sb * cc,  r21 = sa * cc + ca * sb * sc,  r22 = ca * cb;
    float* o = Rt + 12 * v;
    o[0] = -f * r00;  o[1] = -f * r01;  o[2] = -f * r02;
    o[3] =  f * r10;  o[4] =  f * r11;  o[5] =  f * r12;
    o[6] =  r20;      o[7] =  r21;      o[8] =  r22;
    o[9]  = -f * trans[3 * v + 0];
    o[10] =  f * trans[3 * v + 1];
    o[11] =  trans[3 * v + 2];
}

// ---------------------------------------------------------------------------
// Main kernel: one block = one view x 512-point chunk. No view loop -> blocks
// retire in dispatch order, store stream sweeps memory near-sequentially
// (round-1 behavior, which ran at fill-speed 6.8 TB/s effective).
// NT stores: don't allocate output lines in L2, so the 3MB points3d array
// stays L2-resident per XCD across all 128 views (reads ~24MB HBM, not 384MB).
// Each thread: 2 adjacent points; stores float4 uv + float2 z, unit-stride.
// Camera params via wave-uniform s_loads from the 6KB Rt table (K$-hot).
// ---------------------------------------------------------------------------
__global__ void __launch_bounds__(256)
proj_kernel(const f32x2* __restrict__ pts2,
            const float* __restrict__ Rt,
            float* __restrict__ out,
            int N, int Npairs, long long VN) {
    const int t = blockIdx.x * blockDim.x + threadIdx.x;
    if (t >= Npairs) return;
    const int v = blockIdx.y;

    const float* __restrict__ p = Rt + 12 * v;
    const float m0 = p[0], m1 = p[1], m2 = p[2];
    const float m3 = p[3], m4 = p[4], m5 = p[5];
    const float m6 = p[6], m7 = p[7], m8 = p[8];
    const float c0 = p[9], c1 = p[10], c2 = p[11];

    const bool hasP1 = (2 * t + 1 < N);
    const f32x2 A = pts2[3 * t + 0];
    const f32x2 B = hasP1 ? pts2[3 * t + 1] : f32x2{0.f, 0.f};
    const f32x2 C = hasP1 ? pts2[3 * t + 2] : f32x2{pts2[3 * t + 1].x, 0.f};
    const float x0 = A.x, y0 = A.y;
    const float z0 = hasP1 ? B.x : C.x;
    const float x1 = B.y, y1 = C.x, z1 = C.y;

    const float X0 = fmaf(m0, x0, fmaf(m1, y0, fmaf(m2, z0, c0)));
    const float Y0 = fmaf(m3, x0, fmaf(m4, y0, fmaf(m5, z0, c1)));
    const float Z0 = fmaf(m6, x0, fmaf(m7, y0, fmaf(m8, z0, c2)));
    const float r0 = __builtin_amdgcn_rcpf(Z0);
    const float u0 = fmaf(X0, r0, PCX);
    const float w0 = fmaf(Y0, r0, PCY);

    const float X1 = fmaf(m0, x1, fmaf(m1, y1, fmaf(m2, z1, c0)));
    const float Y1 = fmaf(m3, x1, fmaf(m4, y1, fmaf(m5, z1, c1)));
    const float Z1 = fmaf(m6, x1, fmaf(m7, y1, fmaf(m8, z1, c2)));
    const float r1 = __builtin_amdgcn_rcpf(Z1);
    const float u1 = fmaf(X1, r1, PCX);
    const float w1 = fmaf(Y1, r1, PCY);

    if (((N & 1) == 0) && hasP1) {
        f32x4 uvv; uvv.x = u0; uvv.y = w0; uvv.z = u1; uvv.w = w1;
        f32x2 zz;  zz.x = Z0;  zz.y = Z1;
        const int halfN = N >> 1;
        __builtin_nontemporal_store(uvv,
            reinterpret_cast<f32x4*>(out) + (long long)v * halfN + t);
        __builtin_nontemporal_store(zz,
            reinterpret_cast<f32x2*>(out + 2 * VN) + (long long)v * halfN + t);
    } else {
        const long long idx = (long long)v * N + 2LL * t;
        out[2 * idx + 0] = u0;
        out[2 * idx + 1] = w0;
        out[2 * VN + idx] = Z0;
        if (hasP1) {
            out[2 * idx + 2] = u1;
            out[2 * idx + 3] = w1;
            out[2 * VN + idx + 1] = Z1;
        }
    }
}

extern "C" void kernel_launch(void* const* d_in, const int* in_sizes, int n_in,
                              void* d_out, int out_size, void* d_ws, size_t ws_size,
                              hipStream_t stream) {
    const float* focal  = (const float*)d_in[0];
    const float* eulers = (const float*)d_in[1];
    const float* trans  = (const float*)d_in[2];
    const float* pts    = (const float*)d_in[3];

    const int V = in_sizes[1] / 3;
    const int N = in_sizes[3] / 3;
    const int Npairs = (N + 1) / 2;
    const long long VN = (long long)V * N;

    float* out = (float*)d_out;
    float* Rt  = (float*)d_ws;   // 12*V floats

    setup_R_kernel<<<dim3((V + 63) / 64), dim3(64), 0, stream>>>(
        eulers, trans, focal, Rt, V);

    dim3 block(256, 1, 1);
    dim3 grid((Npairs + 255) / 256, V, 1);
    proj_kernel<<<grid, block, 0, stream>>>(
        reinterpret_cast<const f32x2*>(pts), Rt, out, N, Npairs, VN);
}